// Round 15
// baseline (215.508 us; speedup 1.0000x reference)
//
#include <hip/hip_runtime.h>
#include <math.h>

// B=2, S=2048, D=768, H=12, Dh=64, F=3072, PD=64
typedef unsigned short u16;
typedef short bf8 __attribute__((ext_vector_type(8)));
typedef float f4 __attribute__((ext_vector_type(4)));

#define LOG2E 1.44269504088896340736f

__device__ __forceinline__ u16 f2b(float f) {
  union { float f; unsigned int u; } v; v.f = f;
  unsigned int u = v.u;
  return (u16)((u + 0x7FFFu + ((u >> 16) & 1u)) >> 16);
}
__device__ __forceinline__ float b2f(u16 u) {
  union { unsigned int i; float f; } v; v.i = ((unsigned int)u) << 16; return v.f;
}
__device__ __forceinline__ float ex2(float x) {
#if __has_builtin(__builtin_amdgcn_exp2f)
  return __builtin_amdgcn_exp2f(x);
#else
  return exp2f(x);
#endif
}
__device__ __forceinline__ float rcp_f(float x) {
#if __has_builtin(__builtin_amdgcn_rcpf)
  return __builtin_amdgcn_rcpf(x);
#else
  return 1.0f / x;
#endif
}
// exact identity tanh via exp2+rcp (graceful at +-inf)
__device__ __forceinline__ float fast_tanh(float y) {
  return 1.0f - 2.0f * rcp_f(ex2(y * (2.0f * LOG2E)) + 1.0f);
}
// tanh-form GELU (max abs err ~1e-3; downstream scale 0.02 -> negligible)
__device__ __forceinline__ float fast_gelu(float v) {
  const float u = v * (0.79788456080286536f + 0.03567740814f * v * v);
  return 0.5f * v * (1.0f + fast_tanh(u));
}

// counted vmcnt wait (immediate must be a literal)
template <int N>
__device__ __forceinline__ void waitvm() {
  if constexpr (N == 0)      asm volatile("s_waitcnt vmcnt(0)" ::: "memory");
  else if constexpr (N == 4) asm volatile("s_waitcnt vmcnt(4)" ::: "memory");
  else if constexpr (N == 6) asm volatile("s_waitcnt vmcnt(6)" ::: "memory");
  else if constexpr (N == 8) asm volatile("s_waitcnt vmcnt(8)" ::: "memory");
}

#define GLOAD_LDS16(gp, lp)                                                          \
  __builtin_amdgcn_global_load_lds(                                                  \
      reinterpret_cast<const __attribute__((address_space(1))) unsigned int*>(       \
          reinterpret_cast<uintptr_t>(gp)),                                          \
      reinterpret_cast<__attribute__((address_space(3))) unsigned int*>(             \
          reinterpret_cast<uintptr_t>(lp)),                                          \
      16, 0, 0)

// ---- swizzled [R][64]-bf16 tile helpers (128B rows, 8 chunks) ----
// LDS layout: byte(row, chunk) = row*128 + ((chunk ^ (row&7)) * 16), chunk in [0,8)
template <int ISSUES>
__device__ __forceinline__ void stage_sw(const u16* gbase, long ldg, u16* lds,
                                         int wv, int lane) {
#pragma unroll
  for (int is = 0; is < ISSUES; ++is) {
    const int idx = is * 256 + wv * 64 + lane;
    const int r = idx >> 3, cs = idx & 7;
    const u16* gp = gbase + (long)r * ldg + ((cs ^ (r & 7)) << 3);
    GLOAD_LDS16(gp, (char*)lds + is * 4096 + wv * 1024);
  }
}
__device__ __forceinline__ bf8 frag_sw(const u16* lds, int r, int c) {
  return *(const bf8*)((const char*)lds + r * 128 + ((c ^ (r & 7)) << 4));
}

// ---------------- f32 -> bf16 converter (weights) ----------------
__global__ __launch_bounds__(256) void conv_bf16_k(const float* __restrict__ in,
                                                   u16* __restrict__ out, int n4) {
  int i = blockIdx.x * 256 + threadIdx.x;
  if (i >= n4) return;
  float4 v = ((const float4*)in)[i];
  union { u16 s[4]; uint2 u; } o;
  o.s[0] = f2b(v.x); o.s[1] = f2b(v.y); o.s[2] = f2b(v.z); o.s[3] = f2b(v.w);
  ((uint2*)out)[i] = o.u;
}

// ---------------- LayerNorm f32 in -> bf16 out ----------------
__global__ __launch_bounds__(256) void ln_bf16_k(const float* __restrict__ in,
                                                 const float* __restrict__ w,
                                                 const float* __restrict__ b,
                                                 u16* __restrict__ out) {
  const long row = blockIdx.x;
  const float* xr = in + row * 768;
  const int t = threadIdx.x;
  float v[3];
  float s = 0.f, q = 0.f;
#pragma unroll
  for (int i = 0; i < 3; ++i) {
    v[i] = xr[t + 256 * i];
    s += v[i]; q += v[i] * v[i];
  }
#pragma unroll
  for (int off = 1; off < 64; off <<= 1) { s += __shfl_xor(s, off); q += __shfl_xor(q, off); }
  __shared__ float rs[4], rq[4];
  const int wave = t >> 6, lane = t & 63;
  if (lane == 0) { rs[wave] = s; rq[wave] = q; }
  __syncthreads();
  s = rs[0] + rs[1] + rs[2] + rs[3];
  q = rq[0] + rq[1] + rq[2] + rq[3];
  const float mean = s * (1.0f / 768.0f);
  const float var = q * (1.0f / 768.0f) - mean * mean;
  const float rstd = rsqrtf(var + 1e-5f);
  u16* orow = out + row * 768;
#pragma unroll
  for (int i = 0; i < 3; ++i) {
    const int c = t + 256 * i;
    orow[c] = f2b((v[i] - mean) * rstd * w[c] + b[c]);
  }
}

// ---------------- bf16 transpose [4096][768] -> [768][4096]; also zeros rsum ---------
__global__ __launch_bounds__(256) void transp_k(const u16* __restrict__ in,
                                                u16* __restrict__ out,
                                                float* __restrict__ rsum) {
  const int d0 = blockIdx.x * 64, s0 = blockIdx.y * 64;
  const int t = threadIdx.x;
  {
    const int bid = blockIdx.x + 12 * blockIdx.y;
    if (bid < 16) rsum[bid * 256 + t] = 0.f;
  }
  __shared__ u16 T[64][72];
  {
    const int r = t >> 3, c8 = (t & 7) * 8;
#pragma unroll
    for (int p = 0; p < 2; ++p) {
      const int rr = r + 32 * p;
      *(uint4*)&T[rr][c8] = *(const uint4*)&in[(long)(s0 + rr) * 768 + d0 + c8];
    }
  }
  __syncthreads();
  {
    const int d = t >> 3, s8 = (t & 7) * 8;
#pragma unroll
    for (int p = 0; p < 2; ++p) {
      const int dd = d + 32 * p;
      u16 tmp[8];
#pragma unroll
      for (int e = 0; e < 8; ++e) tmp[e] = T[s8 + e][dd];
      *(uint4*)&out[(long)(d0 + dd) * 4096 + s0 + s8] = *(uint4*)tmp;
    }
  }
}

// ---------------- MFMA GEMM v7: C = A[M,K] @ Bt[N,K]^T ----------------
// TM x 128 tile, BK=64, SINGLE-buffer XOR-swizzled LDS with frag-first schedule:
// {read 16 frags -> lgkmcnt(0)+barrier -> stage kt+1 into same buf -> MFMA -> vmcnt(0)
//  + barrier}. LDS 32KB (TM=128) / 24KB (TM=64) -> ~3 blocks/CU (12 waves) vs dbuf's 2.
// Pointer-increment staging, hoisted frag offsets, XCD-chunk + group-N decode (G=8).
// EPI: 0 = merged proj: col<768 -> q*(0.125*log2e); <1536 -> k; <1600 -> tanh -> phase
//      3 = bias + gelu -> O0 bf16
//      4 = bias + res -> O0 f32
//      5 = rowscale by rcp(rsum) + res -> O0 f32 (PV: bias arg = rsum[bz*M+row])
template <int EPI, int TM>
__global__ __launch_bounds__(256) void mgemm7_k(
    const u16* __restrict__ A, int lda, long sA,
    const u16* __restrict__ B, int ldb, long sB,
    const float* __restrict__ bias,
    const float* __restrict__ res, long sR,
    void* __restrict__ O0, long sO, void* __restrict__ O1, void* __restrict__ O2,
    const int M, const int N, const int K) {
  constexpr int WR = (TM == 128) ? 2 : 1;
  constexpr int WC = 4 / WR;
  constexpr int MR = TM / (WR * 16);      // 4
  constexpr int NR = 128 / (WC * 16);     // 4 (TM=128) or 2 (TM=64)
  constexpr int AISS = TM / 32;           // staging issues per wave for A (BK=64)
  constexpr int BISS = 4;
  __shared__ u16 As[TM * 64];
  __shared__ u16 Bs[128 * 64];
  const int t = threadIdx.x;
  const int wv = t >> 6, lane = t & 63;
  const int lr = lane & 15, lg = lane >> 4;
  const int wr = wv / WC, wc = wv % WC;
  const int wrow0 = wr * (MR * 16), wcol0 = wc * (NR * 16);

  // XCD chunking (nwg%8==0) + triton-style group along N inside the chunk.
  const int gx = gridDim.x, gy = gridDim.y;
  const int nwg = gx * gy;
  const int cpx = nwg >> 3;
  const int flat = blockIdx.x + gx * blockIdx.y;
  const int nf = (flat & 7) * cpx + (flat >> 3);
  constexpr int G = 8;
  const int npg = G * gy;
  const int grp = nf / npg;
  const int firstn = grp * G;
  const int gsz = (gx - firstn < G) ? (gx - firstn) : G;
  const int rem = nf - grp * npg;
  const int m0 = (rem / gsz) * TM;
  const int n0 = (firstn + rem % gsz) * 128;

  const int bz = blockIdx.z;
  const u16* Ab = A + (long)bz * sA + (long)m0 * lda;
  const u16* Bb = B + (long)bz * sB + (long)n0 * ldb;
  const long zR = (long)bz * sR, zO = (long)bz * sO;

  // staging pointers: computed once, advanced by 64 elements per K-step
  const u16* ga[AISS];
  const u16* gb[BISS];
#pragma unroll
  for (int is = 0; is < AISS; ++is) {
    const int idx = is * 256 + wv * 64 + lane;
    const int r = idx >> 3, cs = idx & 7;
    ga[is] = Ab + (long)r * lda + ((cs ^ (r & 7)) << 3);
  }
#pragma unroll
  for (int is = 0; is < BISS; ++is) {
    const int idx = is * 256 + wv * 64 + lane;
    const int r = idx >> 3, cs = idx & 7;
    gb[is] = Bb + (long)r * ldb + ((cs ^ (r & 7)) << 3);
  }

  // hoisted frag byte offsets, s = K-half 0/1
  int offA[2][MR], offB[2][NR];
#pragma unroll
  for (int i = 0; i < MR; ++i) {
    const int r = wrow0 + i * 16 + lr;
    offA[0][i] = r * 128 + ((lg ^ (r & 7)) << 4);
    offA[1][i] = r * 128 + (((4 + lg) ^ (r & 7)) << 4);
  }
#pragma unroll
  for (int j = 0; j < NR; ++j) {
    const int r = wcol0 + j * 16 + lr;
    offB[0][j] = r * 128 + ((lg ^ (r & 7)) << 4);
    offB[1][j] = r * 128 + (((4 + lg) ^ (r & 7)) << 4);
  }

  f4 acc[MR][NR];
  const f4 fz = {0.f, 0.f, 0.f, 0.f};
#pragma unroll
  for (int i = 0; i < MR; ++i)
#pragma unroll
    for (int j = 0; j < NR; ++j) acc[i][j] = fz;

  // prologue: stage tile 0
#pragma unroll
  for (int is = 0; is < AISS; ++is) {
    GLOAD_LDS16(ga[is], (char*)As + is * 4096 + wv * 1024);
    ga[is] += 64;
  }
#pragma unroll
  for (int is = 0; is < BISS; ++is) {
    GLOAD_LDS16(gb[is], (char*)Bs + is * 4096 + wv * 1024);
    gb[is] += 64;
  }
  asm volatile("s_waitcnt vmcnt(0)" ::: "memory");
  __builtin_amdgcn_s_barrier();

  const int NT = K >> 6;
  for (int kt = 0; kt < NT; ++kt) {
    // 1) pull this tile's fragments into registers
    bf8 af[2][MR], bf[2][NR];
#pragma unroll
    for (int s = 0; s < 2; ++s) {
#pragma unroll
      for (int i = 0; i < MR; ++i) af[s][i] = *(const bf8*)((const char*)As + offA[s][i]);
#pragma unroll
      for (int j = 0; j < NR; ++j) bf[s][j] = *(const bf8*)((const char*)Bs + offB[s][j]);
    }
    asm volatile("s_waitcnt lgkmcnt(0)" ::: "memory");
    __builtin_amdgcn_sched_barrier(0);
    __builtin_amdgcn_s_barrier();     // all waves hold frags; LDS reusable
    // 2) stage next tile into the same buffer (flies under the MFMAs)
    if (kt + 1 < NT) {
#pragma unroll
      for (int is = 0; is < AISS; ++is) {
        GLOAD_LDS16(ga[is], (char*)As + is * 4096 + wv * 1024);
        ga[is] += 64;
      }
#pragma unroll
      for (int is = 0; is < BISS; ++is) {
        GLOAD_LDS16(gb[is], (char*)Bs + is * 4096 + wv * 1024);
        gb[is] += 64;
      }
    }
    // 3) compute from registers
#pragma unroll
    for (int s = 0; s < 2; ++s)
#pragma unroll
      for (int i = 0; i < MR; ++i)
#pragma unroll
        for (int j = 0; j < NR; ++j)
          acc[i][j] = __builtin_amdgcn_mfma_f32_16x16x32_bf16(af[s][i], bf[s][j], acc[i][j], 0, 0, 0);
    asm volatile("s_waitcnt vmcnt(0)" ::: "memory");  // next tile landed
    __builtin_amdgcn_s_barrier();
  }

#pragma unroll
  for (int i = 0; i < MR; ++i) {
    const int gr0 = m0 + wrow0 + i * 16 + lg * 4;
#pragma unroll
    for (int j = 0; j < NR; ++j) {
      const int gc = n0 + wcol0 + j * 16 + lr;
#pragma unroll
      for (int r = 0; r < 4; ++r) {
        const long row = gr0 + r;
        float v = acc[i][j][r];
        if (EPI == 0) {
          if (gc < 1536) {
            v += bias[gc];
            if (gc < 768) ((u16*)O0)[row * 768 + gc] = f2b(v * (0.125f * LOG2E));
            else          ((u16*)O1)[row * 768 + gc - 768] = f2b(v);
          } else if (gc < 1600) {
            ((u16*)O2)[row * 64 + gc - 1536] = f2b(fast_tanh(v));
          }
        } else if (EPI == 3) {
          ((u16*)O0)[row * N + gc] = f2b(fast_gelu(v + bias[gc]));
        } else if (EPI == 4) {
          ((float*)O0)[row * N + gc] = v + bias[gc] + res[row * N + gc];
        } else {  // 5: rowscale by rcp(rsum) + residual (PV)
          const float sc = rcp_f(bias[(long)bz * M + row]);
          ((float*)O0)[zO + row * N + gc] = v * sc + res[zR + row * N + gc];
        }
      }
    }
  }
}

// ---------------- attention stats v4: XCD-grouped 1D grid ---------------------------
// M2[b,h,q] = log2(12 * sum_k exp2(s2)). 1D grid 768: XCD s=bid&7 owns 3 (h,b)
// combos x 32 qt -> per-XCD working set ~1.5MB (L2-resident K/Q slices).
__global__ __launch_bounds__(256) void attn_stats4(const u16* __restrict__ qb,
                                                   const u16* __restrict__ kb,
                                                   float* __restrict__ Ms_g) {
  const int bid = blockIdx.x;
  const int s8 = bid & 7, idx = bid >> 3;        // idx in [0,96)
  const int qt = idx & 31;
  const int combo = s8 * 3 + (idx >> 5);         // [0,24)
  const int h = combo % 12, b = combo / 12;
  const int t = threadIdx.x, wv = t >> 6, lane = t & 63;
  const int lr = lane & 15, lg = lane >> 4;
  __shared__ u16 Qs[64 * 64];
  __shared__ u16 Ks[2][128 * 64];
  __shared__ float zbuf[4][64];
  const long q0 = (long)b * 2048 + qt * 64;
  const long kbase = ((long)b * 2048) * 768 + h * 64;
  stage_sw<2>(qb + q0 * 768 + h * 64, 768, Qs, wv, lane);
  stage_sw<4>(kb + kbase, 768, Ks[0], wv, lane);
  waitvm<4>();  // Q's 2 loads retired (FIFO); K0's 4 may stay in flight
  __builtin_amdgcn_s_barrier();

  bf8 aq[4][2];
#pragma unroll
  for (int i = 0; i < 4; ++i)
#pragma unroll
    for (int kk = 0; kk < 2; ++kk)
      aq[i][kk] = frag_sw(Qs, i * 16 + lr, kk * 4 + lg);

  float zp[4][4];
#pragma unroll
  for (int i = 0; i < 4; ++i)
#pragma unroll
    for (int r = 0; r < 4; ++r) zp[i][r] = 0.f;

  const f4 fz = {0.f, 0.f, 0.f, 0.f};
  int cur = 0;
  for (int kt = 0; kt < 16; ++kt) {
    if (kt < 15) {
      stage_sw<4>(kb + kbase + (long)(kt + 1) * 128 * 768, 768, Ks[cur ^ 1], wv, lane);
      waitvm<4>();
    } else {
      waitvm<0>();
    }
    __builtin_amdgcn_s_barrier();
#pragma unroll
    for (int j = 0; j < 2; ++j) {
      const int krow = wv * 32 + j * 16 + lr;
      const bf8 b0 = frag_sw(Ks[cur], krow, lg);
      const bf8 b1 = frag_sw(Ks[cur], krow, 4 + lg);
#pragma unroll
      for (int i = 0; i < 4; ++i) {
        f4 s = fz;
        s = __builtin_amdgcn_mfma_f32_16x16x32_bf16(aq[i][0], b0, s, 0, 0, 0);
        s = __builtin_amdgcn_mfma_f32_16x16x32_bf16(aq[i][1], b1, s, 0, 0, 0);
#pragma unroll
        for (int r = 0; r < 4; ++r) zp[i][r] += ex2(s[r]);
      }
    }
    __builtin_amdgcn_s_barrier();
    cur ^= 1;
  }
#pragma unroll
  for (int i = 0; i < 4; ++i)
#pragma unroll
    for (int r = 0; r < 4; ++r) {
      float z = zp[i][r];
      z += __shfl_xor(z, 1); z += __shfl_xor(z, 2);
      z += __shfl_xor(z, 4); z += __shfl_xor(z, 8);
      zp[i][r] = z;
    }
  if (lr == 0) {
#pragma unroll
    for (int i = 0; i < 4; ++i)
#pragma unroll
      for (int r = 0; r < 4; ++r)
        zbuf[wv][i * 16 + lg * 4 + r] = zp[i][r];
  }
  __syncthreads();
  if (t < 64) {
    const float Z = zbuf[0][t] + zbuf[1][t] + zbuf[2][t] + zbuf[3][t];
    Ms_g[((long)(b * 12 + h)) * 2048 + qt * 64 + t] = log2f(12.0f * Z);
  }
}

// ---------------- blend-pre v10: XCD-grouped 1D grid, dbuf counted-vmcnt --------------
// 1D grid 512: XCD s=bid&7 owns one 8x8 (kt x qt) square (s = b*4 + qth*2 + kth),
// per-XCD per-head working set = 8 Q + 8 K panels = 256KB -> L2-resident.
// e = (sum_h exp2(s2 - M2_h) + 1e-6) * exp2(alpha*log2e*0.5*(coh+1))  [bf16 out]
// rsum[b*2048+q] += row partials (f32, atomic). 128q x 128k tiles, 256 thr.
__global__ __launch_bounds__(256) void blendpre10(const u16* __restrict__ qb,
                                                  const u16* __restrict__ kb,
                                                  const u16* __restrict__ ph,
                                                  const float* __restrict__ Ms_g,
                                                  const float* __restrict__ alpha_p,
                                                  u16* __restrict__ eb,
                                                  float* __restrict__ rsum) {
  const int bid = blockIdx.x;
  const int s8 = bid & 7, idx = bid >> 3;        // idx in [0,64)
  const int kt = ((s8 & 1) << 3) | (idx & 7);
  const int qt = (((s8 >> 1) & 1) << 3) | (idx >> 3);
  const int b = s8 >> 2;
  const int t = threadIdx.x, wv = t >> 6, lane = t & 63;
  const int lr = lane & 15, lg = lane >> 4;
  const int wr = wv >> 1, wc = wv & 1;
  const int q0 = qt * 128, k0 = kt * 128;
  __shared__ u16 Qs[2][128 * 64];
  __shared__ u16 Ks[2][128 * 64];
  __shared__ float Ms[12][128];
  for (int i2 = t; i2 < 1536; i2 += 256)
    Ms[i2 >> 7][i2 & 127] = Ms_g[((long)(b * 12 + (i2 >> 7))) * 2048 + q0 + (i2 & 127)];
  asm volatile("s_waitcnt vmcnt(0) lgkmcnt(0)" ::: "memory");
  __builtin_amdgcn_s_barrier();   // Ms visible to all waves
  const float a2 = alpha_p[0] * 0.5f * LOG2E;

  f4 acc[4][4];
  const f4 fz = {0.f, 0.f, 0.f, 0.f};
#pragma unroll
  for (int i = 0; i < 4; ++i)
#pragma unroll
    for (int j = 0; j < 4; ++j) acc[i][j] = fz;

  const long qrow0 = (long)b * 2048 + q0;
  const long krow0 = (long)b * 2048 + k0;

  stage_sw<4>(qb + qrow0 * 768, 768, Qs[0], wv, lane);
  stage_sw<4>(kb + krow0 * 768, 768, Ks[0], wv, lane);

  int cur = 0;
  for (int h = 0; h < 12; ++h) {
    if (h < 11) {
      stage_sw<4>(qb + qrow0 * 768 + (h + 1) * 64, 768, Qs[cur ^ 1], wv, lane);
      stage_sw<4>(kb + krow0 * 768 + (h + 1) * 64, 768, Ks[cur ^ 1], wv, lane);
      waitvm<8>();
    } else {
      waitvm<0>();
    }
    __builtin_amdgcn_s_barrier();
    bf8 aq0[4], aq1[4], bk0[4], bk1[4];
#pragma unroll
    for (int i = 0; i < 4; ++i) {
      aq0[i] = frag_sw(Qs[cur], wr * 64 + i * 16 + lr, lg);
      aq1[i] = frag_sw(Qs[cur], wr * 64 + i * 16 + lr, 4 + lg);
    }
#pragma unroll
    for (int j = 0; j < 4; ++j) {
      bk0[j] = frag_sw(Ks[cur], wc * 64 + j * 16 + lr, lg);
      bk1[j] = frag_sw(Ks[cur], wc * 64 + j * 16 + lr, 4 + lg);
    }
#pragma unroll
    for (int i = 0; i < 4; ++i) {
      const f4 mv = *(const f4*)&Ms[h][wr * 64 + i * 16 + lg * 4];
      const f4 cin = fz - mv;  // fold -M into the accumulator init
#pragma unroll
      for (int j = 0; j < 4; ++j) {
        f4 s = __builtin_amdgcn_mfma_f32_16x16x32_bf16(aq0[i], bk0[j], cin, 0, 0, 0);
        s = __builtin_amdgcn_mfma_f32_16x16x32_bf16(aq1[i], bk1[j], s, 0, 0, 0);
#pragma unroll
        for (int r = 0; r < 4; ++r) acc[i][j][r] += ex2(s[r]);
      }
    }
    __builtin_amdgcn_s_barrier();
    cur ^= 1;
  }

  float rs[4][4];
#pragma unroll
  for (int i = 0; i < 4; ++i)
#pragma unroll
    for (int r = 0; r < 4; ++r) rs[i][r] = 0.f;

#pragma unroll
  for (int i = 0; i < 4; ++i) {
    const u16* pa = ph + (qrow0 + wr * 64 + i * 16 + lr) * 64;
    const bf8 pa0 = *(const bf8*)(pa + lg * 8);
    const bf8 pa1 = *(const bf8*)(pa + 32 + lg * 8);
#pragma unroll
    for (int j = 0; j < 4; ++j) {
      const u16* pb = ph + (krow0 + wc * 64 + j * 16 + lr) * 64;
      const bf8 pb0 = *(const bf8*)(pb + lg * 8);
      const bf8 pb1 = *(const bf8*)(pb + 32 + lg * 8);
      f4 coh = fz;
      coh = __builtin_amdgcn_mfma_f32_16x16x32_bf16(pa0, pb0, coh, 0, 0, 0);
      coh = __builtin_amdgcn_mfma_f32_16x16x32_bf16(pa1, pb1, coh, 0, 0, 0);
#pragma unroll
      for (int r = 0; r < 4; ++r) {
        const long row = qrow0 + wr * 64 + i * 16 + lg * 4 + r;
        const int col = k0 + wc * 64 + j * 16 + lr;
        const float e = (acc[i][j][r] + 1e-6f) * ex2(a2 * (coh[r] + 1.0f));
        eb[row * 2048 + col] = f2b(e);
        rs[i][r] += e;
      }
    }
  }
  // per-row partial sums: reduce over the 16 lanes sharing (lg, row), one atomic each
#pragma unroll
  for (int i = 0; i < 4; ++i)
#pragma unroll
    for (int r = 0; r < 4; ++r) {
      float v = rs[i][r];
      v += __shfl_xor(v, 1); v += __shfl_xor(v, 2);
      v += __shfl_xor(v, 4); v += __shfl_xor(v, 8);
      if (lr == 0)
        atomicAdd(&rsum[qrow0 + wr * 64 + i * 16 + lg * 4 + r], v);
    }
}

// ---------------- launch ----------------
extern "C" void kernel_launch(void* const* d_in, const int* in_sizes, int n_in,
                              void* d_out, int out_size, void* d_ws, size_t ws_size,
                              hipStream_t stream) {
  (void)in_sizes; (void)n_in; (void)out_size; (void)ws_size;
  const float* x         = (const float*)d_in[0];
  const float* ln1_w     = (const float*)d_in[1];
  const float* ln1_b     = (const float*)d_in[2];
  const float* in_proj_w = (const float*)d_in[3];
  const float* in_proj_b = (const float*)d_in[4];
  const float* phase_w   = (const float*)d_in[5];
  const float* alpha_p   = (const float*)d_in[6];
  const float* ff_w1     = (const float*)d_in[7];
  const float* ff_b1     = (const float*)d_in[8];
  const float* ff_w2     = (const float*)d_in[9];
  const float* ff_b2     = (const float*)d_in[10];
  const float* ln2_w     = (const float*)d_in[11];
  const float* ln2_b     = (const float*)d_in[12];
  float* out = (float*)d_out;

  char* w = (char*)d_ws;
  u16*   xn_b  = (u16*)w;            w += 6291456;   // [4096][768] bf16
  u16*   xnT_b = (u16*)w;            w += 6291456;   // [768][4096] bf16
  u16*   ph_b  = (u16*)w;            w += 524288;    // [4096][64] bf16
  float* Ms_g  = (float*)w;          w += 196608;    // [2,12,2048] f32
  float* xmid  = (float*)w;          w += 12582912;  // [4096][768] f32
  char* big = w;
  u16* q_b  = (u16*)big;                              // [4096][768] bf16
  u16* k_b  = (u16*)(big + 6291456);                  // [4096][768] bf16
  u16* eb_b = (u16*)(big + 12582912);                 // [2,2048,2048] bf16 (unnormalized e)
  char* tail = big + 12582912 + 16777216;
  u16* wcat_b = (u16*)tail;                           // [1664][768] bf16 (dead after proj)
  float* rsum = (float*)(tail + 2555904);             // [4096] f32 (row sums)
  u16* h_b  = (u16*)big;                              // [4096][3072] bf16 (overlays q,k,eb)
  char* wtail = tail + 16777216;
  u16* wff1_b = (u16*)wtail;                          // [3072][768] bf16
  u16* wff2_b = (u16*)(wtail + 4718592);              // [768][3072] bf16
  u16* x2n_b = xn_b;

  conv_bf16_k<<<(1536 * 768 / 4 + 255) / 256, 256, 0, stream>>>(in_proj_w, wcat_b, 1536 * 768 / 4);
  conv_bf16_k<<<(64 * 768 / 4 + 255) / 256, 256, 0, stream>>>(phase_w, wcat_b + 1536 * 768, 64 * 768 / 4);
  conv_bf16_k<<<(3072 * 768 / 4 + 255) / 256, 256, 0, stream>>>(ff_w1, wff1_b, 3072 * 768 / 4);
  conv_bf16_k<<<(768 * 3072 / 4 + 255) / 256, 256, 0, stream>>>(ff_w2, wff2_b, 768 * 3072 / 4);

  ln_bf16_k<<<4096, 256, 0, stream>>>(x, ln1_w, ln1_b, xn_b);

  // merged QK + phase projection: N = 1536 (q,k) + 64 (phase) padded to 1664
  mgemm7_k<0, 128><<<dim3(13, 32, 1), 256, 0, stream>>>(
      xn_b, 768, 0, wcat_b, 768, 0, in_proj_b, nullptr, 0,
      q_b, 0, k_b, ph_b, 4096, 1664, 768);

  transp_k<<<dim3(12, 64), 256, 0, stream>>>(xn_b, xnT_b, rsum);

  attn_stats4<<<768, 256, 0, stream>>>(q_b, k_b, Ms_g);

  blendpre10<<<512, 256, 0, stream>>>(q_b, k_b, ph_b, Ms_g, alpha_p, eb_b, rsum);

  mgemm7_k<5, 64><<<dim3(6, 32, 2), 256, 0, stream>>>(
      eb_b, 2048, 2048L * 2048, xnT_b, 4096, 2048, rsum, x, 2048L * 768,
      xmid, 2048L * 768, nullptr, nullptr, 2048, 768, 2048);

  ln_bf16_k<<<4096, 256, 0, stream>>>(xmid, ln2_w, ln2_b, x2n_b);

  mgemm7_k<3, 128><<<dim3(24, 32, 1), 256, 0, stream>>>(
      x2n_b, 768, 0, wff1_b, 768, 0, ff_b1, nullptr, 0,
      h_b, 0, nullptr, nullptr, 4096, 3072, 768);

  mgemm7_k<4, 64><<<dim3(6, 64, 1), 256, 0, stream>>>(
      h_b, 3072, 0, wff2_b, 3072, 0, ff_b2, xmid, 0,
      out, 0, nullptr, nullptr, 4096, 768, 3072);
}

// Round 16
// 189.877 us; speedup vs baseline: 1.1350x; 1.1350x over previous
//
#include <hip/hip_runtime.h>
#include <math.h>

// B=2, S=2048, D=768, H=12, Dh=64, F=3072, PD=64
typedef unsigned short u16;
typedef short bf8 __attribute__((ext_vector_type(8)));
typedef float f4 __attribute__((ext_vector_type(4)));

#define LOG2E 1.44269504088896340736f

__device__ __forceinline__ u16 f2b(float f) {
  union { float f; unsigned int u; } v; v.f = f;
  unsigned int u = v.u;
  return (u16)((u + 0x7FFFu + ((u >> 16) & 1u)) >> 16);
}
__device__ __forceinline__ float b2f(u16 u) {
  union { unsigned int i; float f; } v; v.i = ((unsigned int)u) << 16; return v.f;
}
__device__ __forceinline__ float ex2(float x) {
#if __has_builtin(__builtin_amdgcn_exp2f)
  return __builtin_amdgcn_exp2f(x);
#else
  return exp2f(x);
#endif
}
__device__ __forceinline__ float rcp_f(float x) {
#if __has_builtin(__builtin_amdgcn_rcpf)
  return __builtin_amdgcn_rcpf(x);
#else
  return 1.0f / x;
#endif
}
// exact identity tanh via exp2+rcp (graceful at +-inf)
__device__ __forceinline__ float fast_tanh(float y) {
  return 1.0f - 2.0f * rcp_f(ex2(y * (2.0f * LOG2E)) + 1.0f);
}
// tanh-form GELU (max abs err ~1e-3; downstream scale 0.02 -> negligible)
__device__ __forceinline__ float fast_gelu(float v) {
  const float u = v * (0.79788456080286536f + 0.03567740814f * v * v);
  return 0.5f * v * (1.0f + fast_tanh(u));
}

// counted vmcnt wait (immediate must be a literal)
template <int N>
__device__ __forceinline__ void waitvm() {
  if constexpr (N == 0)      asm volatile("s_waitcnt vmcnt(0)" ::: "memory");
  else if constexpr (N == 4) asm volatile("s_waitcnt vmcnt(4)" ::: "memory");
  else if constexpr (N == 6) asm volatile("s_waitcnt vmcnt(6)" ::: "memory");
  else if constexpr (N == 8) asm volatile("s_waitcnt vmcnt(8)" ::: "memory");
}

#define GLOAD_LDS16(gp, lp)                                                          \
  __builtin_amdgcn_global_load_lds(                                                  \
      reinterpret_cast<const __attribute__((address_space(1))) unsigned int*>(       \
          reinterpret_cast<uintptr_t>(gp)),                                          \
      reinterpret_cast<__attribute__((address_space(3))) unsigned int*>(             \
          reinterpret_cast<uintptr_t>(lp)),                                          \
      16, 0, 0)

// ---- swizzled [R][64]-bf16 tile helpers (128B rows, 8 chunks) ----
// LDS layout: byte(row, chunk) = row*128 + ((chunk ^ (row&7)) * 16), chunk in [0,8)
template <int ISSUES>
__device__ __forceinline__ void stage_sw(const u16* gbase, long ldg, u16* lds,
                                         int wv, int lane) {
#pragma unroll
  for (int is = 0; is < ISSUES; ++is) {
    const int idx = is * 256 + wv * 64 + lane;
    const int r = idx >> 3, cs = idx & 7;
    const u16* gp = gbase + (long)r * ldg + ((cs ^ (r & 7)) << 3);
    GLOAD_LDS16(gp, (char*)lds + is * 4096 + wv * 1024);
  }
}
__device__ __forceinline__ bf8 frag_sw(const u16* lds, int r, int c) {
  return *(const bf8*)((const char*)lds + r * 128 + ((c ^ (r & 7)) << 4));
}

// ---------------- fused f32 -> bf16 converter (all 4 weight tensors, 1 launch) -------
__global__ __launch_bounds__(256) void conv4_k(
    const float* __restrict__ s0, u16* __restrict__ d0, int n0,
    const float* __restrict__ s1, u16* __restrict__ d1, int n1,
    const float* __restrict__ s2, u16* __restrict__ d2, int n2,
    const float* __restrict__ s3, u16* __restrict__ d3, int n3) {
  int i = blockIdx.x * 256 + threadIdx.x;
  const float* s; u16* d;
  if (i < n0) { s = s0; d = d0; }
  else if (i < n0 + n1) { i -= n0; s = s1; d = d1; }
  else if (i < n0 + n1 + n2) { i -= n0 + n1; s = s2; d = d2; }
  else if (i < n0 + n1 + n2 + n3) { i -= n0 + n1 + n2; s = s3; d = d3; }
  else return;
  float4 v = ((const float4*)s)[i];
  union { u16 sh[4]; uint2 u; } o;
  o.sh[0] = f2b(v.x); o.sh[1] = f2b(v.y); o.sh[2] = f2b(v.z); o.sh[3] = f2b(v.w);
  ((uint2*)d)[i] = o.u;
}

// ---------------- LayerNorm (f32 or bf16 in) -> bf16 out ----------------
template <int INF32>
__global__ __launch_bounds__(256) void ln_bf16_k(const void* __restrict__ in,
                                                 const float* __restrict__ w,
                                                 const float* __restrict__ b,
                                                 u16* __restrict__ out) {
  const long row = blockIdx.x;
  const int t = threadIdx.x;
  float v[3];
  float s = 0.f, q = 0.f;
#pragma unroll
  for (int i = 0; i < 3; ++i) {
    if (INF32) v[i] = ((const float*)in)[row * 768 + t + 256 * i];
    else       v[i] = b2f(((const u16*)in)[row * 768 + t + 256 * i]);
    s += v[i]; q += v[i] * v[i];
  }
#pragma unroll
  for (int off = 1; off < 64; off <<= 1) { s += __shfl_xor(s, off); q += __shfl_xor(q, off); }
  __shared__ float rs[4], rq[4];
  const int wave = t >> 6, lane = t & 63;
  if (lane == 0) { rs[wave] = s; rq[wave] = q; }
  __syncthreads();
  s = rs[0] + rs[1] + rs[2] + rs[3];
  q = rq[0] + rq[1] + rq[2] + rq[3];
  const float mean = s * (1.0f / 768.0f);
  const float var = q * (1.0f / 768.0f) - mean * mean;
  const float rstd = rsqrtf(var + 1e-5f);
  u16* orow = out + row * 768;
#pragma unroll
  for (int i = 0; i < 3; ++i) {
    const int c = t + 256 * i;
    orow[c] = f2b((v[i] - mean) * rstd * w[c] + b[c]);
  }
}

// ---------------- bf16 transpose [4096][768] -> [768][4096]; also zeros rsum ---------
__global__ __launch_bounds__(256) void transp_k(const u16* __restrict__ in,
                                                u16* __restrict__ out,
                                                float* __restrict__ rsum) {
  const int d0 = blockIdx.x * 64, s0 = blockIdx.y * 64;
  const int t = threadIdx.x;
  {
    const int bid = blockIdx.x + 12 * blockIdx.y;
    if (bid < 16) rsum[bid * 256 + t] = 0.f;
  }
  __shared__ u16 T[64][72];
  {
    const int r = t >> 3, c8 = (t & 7) * 8;
#pragma unroll
    for (int p = 0; p < 2; ++p) {
      const int rr = r + 32 * p;
      *(uint4*)&T[rr][c8] = *(const uint4*)&in[(long)(s0 + rr) * 768 + d0 + c8];
    }
  }
  __syncthreads();
  {
    const int d = t >> 3, s8 = (t & 7) * 8;
#pragma unroll
    for (int p = 0; p < 2; ++p) {
      const int dd = d + 32 * p;
      u16 tmp[8];
#pragma unroll
      for (int e = 0; e < 8; ++e) tmp[e] = T[s8 + e][dd];
      *(uint4*)&out[(long)(d0 + dd) * 4096 + s0 + s8] = *(uint4*)tmp;
    }
  }
}

// ---------------- MFMA GEMM (round-14 dbuf counted-vmcnt, proven): -------------------
// C = A[M,K] @ Bt[N,K]^T. TM x 128 tile, BK=64, dbuf XOR-swizzled LDS, counted vmcnt,
// pointer-increment staging, hoisted frag offsets, XCD-chunk + group-N decode (G=8).
// EPI: 0 = merged proj: col<768 -> q*(0.125*log2e); <1536 -> k; <1600 -> tanh -> phase
//      3 = bias + gelu -> O0 bf16
//      5 = rowscale by rcp(rsum) + f32 res -> O0 bf16 (PV; bias arg = rsum[bz*M+row])
//      6 = bias + bf16 res -> O0 f32 (FF2; res points to bf16)
template <int EPI, int TM>
__global__ __launch_bounds__(256) void mgemm5_k(
    const u16* __restrict__ A, int lda, long sA,
    const u16* __restrict__ B, int ldb, long sB,
    const float* __restrict__ bias,
    const float* __restrict__ res, long sR,
    void* __restrict__ O0, long sO, void* __restrict__ O1, void* __restrict__ O2,
    const int M, const int N, const int K) {
  constexpr int WR = (TM == 128) ? 2 : 1;
  constexpr int WC = 4 / WR;
  constexpr int MR = TM / (WR * 16);      // 4
  constexpr int NR = 128 / (WC * 16);     // 4 (TM=128) or 2 (TM=64)
  constexpr int AISS = TM / 32;           // staging issues per wave for A (BK=64)
  constexpr int BISS = 4;
  constexpr int NS = AISS + BISS;         // loads in flight for one tile
  constexpr int AW = TM * 64;             // elements per A buffer
  constexpr int BW = 128 * 64;
  __shared__ u16 As[2 * AW];
  __shared__ u16 Bs[2 * BW];
  const int t = threadIdx.x;
  const int wv = t >> 6, lane = t & 63;
  const int lr = lane & 15, lg = lane >> 4;
  const int wr = wv / WC, wc = wv % WC;
  const int wrow0 = wr * (MR * 16), wcol0 = wc * (NR * 16);

  // XCD chunking (nwg%8==0) + triton-style group along N inside the chunk.
  const int gx = gridDim.x, gy = gridDim.y;
  const int nwg = gx * gy;
  const int cpx = nwg >> 3;
  const int flat = blockIdx.x + gx * blockIdx.y;
  const int nf = (flat & 7) * cpx + (flat >> 3);
  constexpr int G = 8;
  const int npg = G * gy;
  const int grp = nf / npg;
  const int firstn = grp * G;
  const int gsz = (gx - firstn < G) ? (gx - firstn) : G;
  const int rem = nf - grp * npg;
  const int m0 = (rem / gsz) * TM;
  const int n0 = (firstn + rem % gsz) * 128;

  const int bz = blockIdx.z;
  const u16* Ab = A + (long)bz * sA + (long)m0 * lda;
  const u16* Bb = B + (long)bz * sB + (long)n0 * ldb;
  const long zR = (long)bz * sR, zO = (long)bz * sO;

  // staging pointers: computed once, advanced by 64 elements per K-step
  const u16* ga[AISS];
  const u16* gb[BISS];
#pragma unroll
  for (int is = 0; is < AISS; ++is) {
    const int idx = is * 256 + wv * 64 + lane;
    const int r = idx >> 3, cs = idx & 7;
    ga[is] = Ab + (long)r * lda + ((cs ^ (r & 7)) << 3);
  }
#pragma unroll
  for (int is = 0; is < BISS; ++is) {
    const int idx = is * 256 + wv * 64 + lane;
    const int r = idx >> 3, cs = idx & 7;
    gb[is] = Bb + (long)r * ldb + ((cs ^ (r & 7)) << 3);
  }

  // hoisted frag byte offsets (within one buffer), s = K-half 0/1
  int offA[2][MR], offB[2][NR];
#pragma unroll
  for (int i = 0; i < MR; ++i) {
    const int r = wrow0 + i * 16 + lr;
    offA[0][i] = r * 128 + ((lg ^ (r & 7)) << 4);
    offA[1][i] = r * 128 + (((4 + lg) ^ (r & 7)) << 4);
  }
#pragma unroll
  for (int j = 0; j < NR; ++j) {
    const int r = wcol0 + j * 16 + lr;
    offB[0][j] = r * 128 + ((lg ^ (r & 7)) << 4);
    offB[1][j] = r * 128 + (((4 + lg) ^ (r & 7)) << 4);
  }

  f4 acc[MR][NR];
  const f4 fz = {0.f, 0.f, 0.f, 0.f};
#pragma unroll
  for (int i = 0; i < MR; ++i)
#pragma unroll
    for (int j = 0; j < NR; ++j) acc[i][j] = fz;

  // prologue: stage tile 0 into buf 0
#pragma unroll
  for (int is = 0; is < AISS; ++is) {
    GLOAD_LDS16(ga[is], (char*)As + is * 4096 + wv * 1024);
    ga[is] += 64;
  }
#pragma unroll
  for (int is = 0; is < BISS; ++is) {
    GLOAD_LDS16(gb[is], (char*)Bs + is * 4096 + wv * 1024);
    gb[is] += 64;
  }

  const int NT = K >> 6;
  int cur = 0;
  for (int kt = 0; kt < NT; ++kt) {
    if (kt + 1 < NT) {
      char* bufA = (char*)(As + (cur ^ 1) * AW);
      char* bufB = (char*)(Bs + (cur ^ 1) * BW);
#pragma unroll
      for (int is = 0; is < AISS; ++is) {
        GLOAD_LDS16(ga[is], bufA + is * 4096 + wv * 1024);
        ga[is] += 64;
      }
#pragma unroll
      for (int is = 0; is < BISS; ++is) {
        GLOAD_LDS16(gb[is], bufB + is * 4096 + wv * 1024);
        gb[is] += 64;
      }
      waitvm<NS>();   // tile kt landed; tile kt+1 stays in flight
    } else {
      waitvm<0>();
    }
    __builtin_amdgcn_s_barrier();
    const char* a = (const char*)(As + cur * AW);
    const char* b = (const char*)(Bs + cur * BW);
    bf8 af[2][MR], bf[2][NR];
#pragma unroll
    for (int s = 0; s < 2; ++s) {
#pragma unroll
      for (int i = 0; i < MR; ++i) af[s][i] = *(const bf8*)(a + offA[s][i]);
#pragma unroll
      for (int j = 0; j < NR; ++j) bf[s][j] = *(const bf8*)(b + offB[s][j]);
    }
#pragma unroll
    for (int s = 0; s < 2; ++s)
#pragma unroll
      for (int i = 0; i < MR; ++i)
#pragma unroll
        for (int j = 0; j < NR; ++j)
          acc[i][j] = __builtin_amdgcn_mfma_f32_16x16x32_bf16(af[s][i], bf[s][j], acc[i][j], 0, 0, 0);
    __builtin_amdgcn_s_barrier();   // WAR: all waves done reading buf[cur]
    cur ^= 1;
  }

#pragma unroll
  for (int i = 0; i < MR; ++i) {
    const int gr0 = m0 + wrow0 + i * 16 + lg * 4;
#pragma unroll
    for (int j = 0; j < NR; ++j) {
      const int gc = n0 + wcol0 + j * 16 + lr;
#pragma unroll
      for (int r = 0; r < 4; ++r) {
        const long row = gr0 + r;
        float v = acc[i][j][r];
        if (EPI == 0) {
          if (gc < 1536) {
            v += bias[gc];
            if (gc < 768) ((u16*)O0)[row * 768 + gc] = f2b(v * (0.125f * LOG2E));
            else          ((u16*)O1)[row * 768 + gc - 768] = f2b(v);
          } else if (gc < 1600) {
            ((u16*)O2)[row * 64 + gc - 1536] = f2b(fast_tanh(v));
          }
        } else if (EPI == 3) {
          ((u16*)O0)[row * N + gc] = f2b(fast_gelu(v + bias[gc]));
        } else if (EPI == 5) {  // PV: rowscale + f32 residual -> bf16 out
          const float sc = rcp_f(bias[(long)bz * M + row]);
          ((u16*)O0)[zO + row * N + gc] = f2b(v * sc + res[zR + row * N + gc]);
        } else {  // 6: FF2: bias + bf16 residual -> f32 out
          ((float*)O0)[row * N + gc] = v + bias[gc] + b2f(((const u16*)res)[row * N + gc]);
        }
      }
    }
  }
}

// ---------------- attention stats v4: XCD-grouped 1D grid ---------------------------
// M2[b,h,q] = log2(12 * sum_k exp2(s2)). 1D grid 768: XCD s=bid&7 owns 3 (h,b)
// combos x 32 qt -> per-XCD working set ~1.5MB (L2-resident K/Q slices).
__global__ __launch_bounds__(256) void attn_stats4(const u16* __restrict__ qb,
                                                   const u16* __restrict__ kb,
                                                   float* __restrict__ Ms_g) {
  const int bid = blockIdx.x;
  const int s8 = bid & 7, idx = bid >> 3;        // idx in [0,96)
  const int qt = idx & 31;
  const int combo = s8 * 3 + (idx >> 5);         // [0,24)
  const int h = combo % 12, b = combo / 12;
  const int t = threadIdx.x, wv = t >> 6, lane = t & 63;
  const int lr = lane & 15, lg = lane >> 4;
  __shared__ u16 Qs[64 * 64];
  __shared__ u16 Ks[2][128 * 64];
  __shared__ float zbuf[4][64];
  const long q0 = (long)b * 2048 + qt * 64;
  const long kbase = ((long)b * 2048) * 768 + h * 64;
  stage_sw<2>(qb + q0 * 768 + h * 64, 768, Qs, wv, lane);
  stage_sw<4>(kb + kbase, 768, Ks[0], wv, lane);
  waitvm<4>();  // Q's 2 loads retired (FIFO); K0's 4 may stay in flight
  __builtin_amdgcn_s_barrier();

  bf8 aq[4][2];
#pragma unroll
  for (int i = 0; i < 4; ++i)
#pragma unroll
    for (int kk = 0; kk < 2; ++kk)
      aq[i][kk] = frag_sw(Qs, i * 16 + lr, kk * 4 + lg);

  float zp[4][4];
#pragma unroll
  for (int i = 0; i < 4; ++i)
#pragma unroll
    for (int r = 0; r < 4; ++r) zp[i][r] = 0.f;

  const f4 fz = {0.f, 0.f, 0.f, 0.f};
  int cur = 0;
  for (int kt = 0; kt < 16; ++kt) {
    if (kt < 15) {
      stage_sw<4>(kb + kbase + (long)(kt + 1) * 128 * 768, 768, Ks[cur ^ 1], wv, lane);
      waitvm<4>();
    } else {
      waitvm<0>();
    }
    __builtin_amdgcn_s_barrier();
#pragma unroll
    for (int j = 0; j < 2; ++j) {
      const int krow = wv * 32 + j * 16 + lr;
      const bf8 b0 = frag_sw(Ks[cur], krow, lg);
      const bf8 b1 = frag_sw(Ks[cur], krow, 4 + lg);
#pragma unroll
      for (int i = 0; i < 4; ++i) {
        f4 s = fz;
        s = __builtin_amdgcn_mfma_f32_16x16x32_bf16(aq[i][0], b0, s, 0, 0, 0);
        s = __builtin_amdgcn_mfma_f32_16x16x32_bf16(aq[i][1], b1, s, 0, 0, 0);
#pragma unroll
        for (int r = 0; r < 4; ++r) zp[i][r] += ex2(s[r]);
      }
    }
    __builtin_amdgcn_s_barrier();
    cur ^= 1;
  }
#pragma unroll
  for (int i = 0; i < 4; ++i)
#pragma unroll
    for (int r = 0; r < 4; ++r) {
      float z = zp[i][r];
      z += __shfl_xor(z, 1); z += __shfl_xor(z, 2);
      z += __shfl_xor(z, 4); z += __shfl_xor(z, 8);
      zp[i][r] = z;
    }
  if (lr == 0) {
#pragma unroll
    for (int i = 0; i < 4; ++i)
#pragma unroll
      for (int r = 0; r < 4; ++r)
        zbuf[wv][i * 16 + lg * 4 + r] = zp[i][r];
  }
  __syncthreads();
  if (t < 64) {
    const float Z = zbuf[0][t] + zbuf[1][t] + zbuf[2][t] + zbuf[3][t];
    Ms_g[((long)(b * 12 + h)) * 2048 + qt * 64 + t] = log2f(12.0f * Z);
  }
}

// ---------------- blend-pre v10: XCD-grouped 1D grid, dbuf counted-vmcnt --------------
// 1D grid 512: XCD s=bid&7 owns one 8x8 (kt x qt) square (s = b*4 + qth*2 + kth),
// per-XCD per-head working set = 8 Q + 8 K panels = 256KB -> L2-resident.
// e = (sum_h exp2(s2 - M2_h) + 1e-6) * exp2(alpha*log2e*0.5*(coh+1))  [bf16 out]
// rsum[b*2048+q] += row partials (f32, atomic). 128q x 128k tiles, 256 thr.
__global__ __launch_bounds__(256) void blendpre10(const u16* __restrict__ qb,
                                                  const u16* __restrict__ kb,
                                                  const u16* __restrict__ ph,
                                                  const float* __restrict__ Ms_g,
                                                  const float* __restrict__ alpha_p,
                                                  u16* __restrict__ eb,
                                                  float* __restrict__ rsum) {
  const int bid = blockIdx.x;
  const int s8 = bid & 7, idx = bid >> 3;        // idx in [0,64)
  const int kt = ((s8 & 1) << 3) | (idx & 7);
  const int qt = (((s8 >> 1) & 1) << 3) | (idx >> 3);
  const int b = s8 >> 2;
  const int t = threadIdx.x, wv = t >> 6, lane = t & 63;
  const int lr = lane & 15, lg = lane >> 4;
  const int wr = wv >> 1, wc = wv & 1;
  const int q0 = qt * 128, k0 = kt * 128;
  __shared__ u16 Qs[2][128 * 64];
  __shared__ u16 Ks[2][128 * 64];
  __shared__ float Ms[12][128];
  for (int i2 = t; i2 < 1536; i2 += 256)
    Ms[i2 >> 7][i2 & 127] = Ms_g[((long)(b * 12 + (i2 >> 7))) * 2048 + q0 + (i2 & 127)];
  asm volatile("s_waitcnt vmcnt(0) lgkmcnt(0)" ::: "memory");
  __builtin_amdgcn_s_barrier();   // Ms visible to all waves
  const float a2 = alpha_p[0] * 0.5f * LOG2E;

  f4 acc[4][4];
  const f4 fz = {0.f, 0.f, 0.f, 0.f};
#pragma unroll
  for (int i = 0; i < 4; ++i)
#pragma unroll
    for (int j = 0; j < 4; ++j) acc[i][j] = fz;

  const long qrow0 = (long)b * 2048 + q0;
  const long krow0 = (long)b * 2048 + k0;

  stage_sw<4>(qb + qrow0 * 768, 768, Qs[0], wv, lane);
  stage_sw<4>(kb + krow0 * 768, 768, Ks[0], wv, lane);

  int cur = 0;
  for (int h = 0; h < 12; ++h) {
    if (h < 11) {
      stage_sw<4>(qb + qrow0 * 768 + (h + 1) * 64, 768, Qs[cur ^ 1], wv, lane);
      stage_sw<4>(kb + krow0 * 768 + (h + 1) * 64, 768, Ks[cur ^ 1], wv, lane);
      waitvm<8>();
    } else {
      waitvm<0>();
    }
    __builtin_amdgcn_s_barrier();
    bf8 aq0[4], aq1[4], bk0[4], bk1[4];
#pragma unroll
    for (int i = 0; i < 4; ++i) {
      aq0[i] = frag_sw(Qs[cur], wr * 64 + i * 16 + lr, lg);
      aq1[i] = frag_sw(Qs[cur], wr * 64 + i * 16 + lr, 4 + lg);
    }
#pragma unroll
    for (int j = 0; j < 4; ++j) {
      bk0[j] = frag_sw(Ks[cur], wc * 64 + j * 16 + lr, lg);
      bk1[j] = frag_sw(Ks[cur], wc * 64 + j * 16 + lr, 4 + lg);
    }
#pragma unroll
    for (int i = 0; i < 4; ++i) {
      const f4 mv = *(const f4*)&Ms[h][wr * 64 + i * 16 + lg * 4];
      const f4 cin = fz - mv;  // fold -M into the accumulator init
#pragma unroll
      for (int j = 0; j < 4; ++j) {
        f4 s = __builtin_amdgcn_mfma_f32_16x16x32_bf16(aq0[i], bk0[j], cin, 0, 0, 0);
        s = __builtin_amdgcn_mfma_f32_16x16x32_bf16(aq1[i], bk1[j], s, 0, 0, 0);
#pragma unroll
        for (int r = 0; r < 4; ++r) acc[i][j][r] += ex2(s[r]);
      }
    }
    __builtin_amdgcn_s_barrier();
    cur ^= 1;
  }

  float rs[4][4];
#pragma unroll
  for (int i = 0; i < 4; ++i)
#pragma unroll
    for (int r = 0; r < 4; ++r) rs[i][r] = 0.f;

#pragma unroll
  for (int i = 0; i < 4; ++i) {
    const u16* pa = ph + (qrow0 + wr * 64 + i * 16 + lr) * 64;
    const bf8 pa0 = *(const bf8*)(pa + lg * 8);
    const bf8 pa1 = *(const bf8*)(pa + 32 + lg * 8);
#pragma unroll
    for (int j = 0; j < 4; ++j) {
      const u16* pb = ph + (krow0 + wc * 64 + j * 16 + lr) * 64;
      const bf8 pb0 = *(const bf8*)(pb + lg * 8);
      const bf8 pb1 = *(const bf8*)(pb + 32 + lg * 8);
      f4 coh = fz;
      coh = __builtin_amdgcn_mfma_f32_16x16x32_bf16(pa0, pb0, coh, 0, 0, 0);
      coh = __builtin_amdgcn_mfma_f32_16x16x32_bf16(pa1, pb1, coh, 0, 0, 0);
#pragma unroll
      for (int r = 0; r < 4; ++r) {
        const long row = qrow0 + wr * 64 + i * 16 + lg * 4 + r;
        const int col = k0 + wc * 64 + j * 16 + lr;
        const float e = (acc[i][j][r] + 1e-6f) * ex2(a2 * (coh[r] + 1.0f));
        eb[row * 2048 + col] = f2b(e);
        rs[i][r] += e;
      }
    }
  }
  // per-row partial sums: reduce over the 16 lanes sharing (lg, row), one atomic each
#pragma unroll
  for (int i = 0; i < 4; ++i)
#pragma unroll
    for (int r = 0; r < 4; ++r) {
      float v = rs[i][r];
      v += __shfl_xor(v, 1); v += __shfl_xor(v, 2);
      v += __shfl_xor(v, 4); v += __shfl_xor(v, 8);
      if (lr == 0)
        atomicAdd(&rsum[qrow0 + wr * 64 + i * 16 + lg * 4 + r], v);
    }
}

// ---------------- launch ----------------
extern "C" void kernel_launch(void* const* d_in, const int* in_sizes, int n_in,
                              void* d_out, int out_size, void* d_ws, size_t ws_size,
                              hipStream_t stream) {
  (void)in_sizes; (void)n_in; (void)out_size; (void)ws_size;
  const float* x         = (const float*)d_in[0];
  const float* ln1_w     = (const float*)d_in[1];
  const float* ln1_b     = (const float*)d_in[2];
  const float* in_proj_w = (const float*)d_in[3];
  const float* in_proj_b = (const float*)d_in[4];
  const float* phase_w   = (const float*)d_in[5];
  const float* alpha_p   = (const float*)d_in[6];
  const float* ff_w1     = (const float*)d_in[7];
  const float* ff_b1     = (const float*)d_in[8];
  const float* ff_w2     = (const float*)d_in[9];
  const float* ff_b2     = (const float*)d_in[10];
  const float* ln2_w     = (const float*)d_in[11];
  const float* ln2_b     = (const float*)d_in[12];
  float* out = (float*)d_out;

  char* w = (char*)d_ws;
  u16*   xn_b  = (u16*)w;            w += 6291456;   // [4096][768] bf16
  u16*   xnT_b = (u16*)w;            w += 6291456;   // [768][4096] bf16
  u16*   ph_b  = (u16*)w;            w += 524288;    // [4096][64] bf16
  float* Ms_g  = (float*)w;          w += 196608;    // [2,12,2048] f32
  u16*   xmid_b = (u16*)w;           w += 12582912;  // [4096][768] bf16 (region kept at old size)
  char* big = w;
  u16* q_b  = (u16*)big;                              // [4096][768] bf16
  u16* k_b  = (u16*)(big + 6291456);                  // [4096][768] bf16
  u16* eb_b = (u16*)(big + 12582912);                 // [2,2048,2048] bf16 (unnormalized e)
  char* tail = big + 12582912 + 16777216;
  u16* wcat_b = (u16*)tail;                           // [1664][768] bf16 (dead after proj)
  float* rsum = (float*)(tail + 2555904);             // [4096] f32 (row sums)
  u16* h_b  = (u16*)big;                              // [4096][3072] bf16 (overlays q,k,eb)
  char* wtail = tail + 16777216;
  u16* wff1_b = (u16*)wtail;                          // [3072][768] bf16
  u16* wff2_b = (u16*)(wtail + 4718592);              // [768][3072] bf16
  u16* x2n_b = xn_b;

  // one fused conversion launch: in_proj(+phase appended) | ff_w1 | ff_w2
  conv4_k<<<(1486848 + 255) / 256, 256, 0, stream>>>(
      in_proj_w, wcat_b, 1536 * 768 / 4,
      phase_w, wcat_b + 1536 * 768, 64 * 768 / 4,
      ff_w1, wff1_b, 3072 * 768 / 4,
      ff_w2, wff2_b, 768 * 3072 / 4);

  ln_bf16_k<1><<<4096, 256, 0, stream>>>(x, ln1_w, ln1_b, xn_b);

  // merged QK + phase projection: N = 1536 (q,k) + 64 (phase) padded to 1664
  mgemm5_k<0, 128><<<dim3(13, 32, 1), 256, 0, stream>>>(
      xn_b, 768, 0, wcat_b, 768, 0, in_proj_b, nullptr, 0,
      q_b, 0, k_b, ph_b, 4096, 1664, 768);

  transp_k<<<dim3(12, 64), 256, 0, stream>>>(xn_b, xnT_b, rsum);

  attn_stats4<<<768, 256, 0, stream>>>(q_b, k_b, Ms_g);

  blendpre10<<<512, 256, 0, stream>>>(q_b, k_b, ph_b, Ms_g, alpha_p, eb_b, rsum);

  // PV: out bf16 (xmid_b), residual x (f32)
  mgemm5_k<5, 64><<<dim3(6, 32, 2), 256, 0, stream>>>(
      eb_b, 2048, 2048L * 2048, xnT_b, 4096, 2048, rsum, x, 2048L * 768,
      xmid_b, 2048L * 768, nullptr, nullptr, 2048, 768, 2048);

  ln_bf16_k<0><<<4096, 256, 0, stream>>>(xmid_b, ln2_w, ln2_b, x2n_b);

  mgemm5_k<3, 128><<<dim3(24, 32, 1), 256, 0, stream>>>(
      x2n_b, 768, 0, wff1_b, 768, 0, ff_b1, nullptr, 0,
      h_b, 0, nullptr, nullptr, 4096, 3072, 768);

  // FF2: bias + bf16 residual (xmid_b) -> f32 out
  mgemm5_k<6, 64><<<dim3(6, 64, 1), 256, 0, stream>>>(
      h_b, 3072, 0, wff2_b, 3072, 0, ff_b2, (const float*)xmid_b, 0,
      out, 0, nullptr, nullptr, 4096, 768, 3072);
}

// Round 17
// 187.844 us; speedup vs baseline: 1.1473x; 1.0108x over previous
//
#include <hip/hip_runtime.h>
#include <math.h>

// B=2, S=2048, D=768, H=12, Dh=64, F=3072, PD=64
typedef unsigned short u16;
typedef short bf8 __attribute__((ext_vector_type(8)));
typedef float f4 __attribute__((ext_vector_type(4)));

#define LOG2E 1.44269504088896340736f

__device__ __forceinline__ u16 f2b(float f) {
  union { float f; unsigned int u; } v; v.f = f;
  unsigned int u = v.u;
  return (u16)((u + 0x7FFFu + ((u >> 16) & 1u)) >> 16);
}
__device__ __forceinline__ float b2f(u16 u) {
  union { unsigned int i; float f; } v; v.i = ((unsigned int)u) << 16; return v.f;
}
__device__ __forceinline__ float ex2(float x) {
#if __has_builtin(__builtin_amdgcn_exp2f)
  return __builtin_amdgcn_exp2f(x);
#else
  return exp2f(x);
#endif
}
__device__ __forceinline__ float rcp_f(float x) {
#if __has_builtin(__builtin_amdgcn_rcpf)
  return __builtin_amdgcn_rcpf(x);
#else
  return 1.0f / x;
#endif
}
// exact identity tanh via exp2+rcp (graceful at +-inf)
__device__ __forceinline__ float fast_tanh(float y) {
  return 1.0f - 2.0f * rcp_f(ex2(y * (2.0f * LOG2E)) + 1.0f);
}
// tanh-form GELU (max abs err ~1e-3; downstream scale 0.02 -> negligible)
__device__ __forceinline__ float fast_gelu(float v) {
  const float u = v * (0.79788456080286536f + 0.03567740814f * v * v);
  return 0.5f * v * (1.0f + fast_tanh(u));
}

// counted vmcnt wait (immediate must be a literal)
template <int N>
__device__ __forceinline__ void waitvm() {
  if constexpr (N == 0)      asm volatile("s_waitcnt vmcnt(0)" ::: "memory");
  else if constexpr (N == 4) asm volatile("s_waitcnt vmcnt(4)" ::: "memory");
  else if constexpr (N == 6) asm volatile("s_waitcnt vmcnt(6)" ::: "memory");
  else if constexpr (N == 8) asm volatile("s_waitcnt vmcnt(8)" ::: "memory");
}

#define GLOAD_LDS16(gp, lp)                                                          \
  __builtin_amdgcn_global_load_lds(                                                  \
      reinterpret_cast<const __attribute__((address_space(1))) unsigned int*>(       \
          reinterpret_cast<uintptr_t>(gp)),                                          \
      reinterpret_cast<__attribute__((address_space(3))) unsigned int*>(             \
          reinterpret_cast<uintptr_t>(lp)),                                          \
      16, 0, 0)

// ---- swizzled [R][64]-bf16 tile helpers (128B rows, 8 chunks; attn kernels) ----
template <int ISSUES>
__device__ __forceinline__ void stage_sw(const u16* gbase, long ldg, u16* lds,
                                         int wv, int lane) {
#pragma unroll
  for (int is = 0; is < ISSUES; ++is) {
    const int idx = is * 256 + wv * 64 + lane;
    const int r = idx >> 3, cs = idx & 7;
    const u16* gp = gbase + (long)r * ldg + ((cs ^ (r & 7)) << 3);
    GLOAD_LDS16(gp, (char*)lds + is * 4096 + wv * 1024);
  }
}
__device__ __forceinline__ bf8 frag_sw(const u16* lds, int r, int c) {
  return *(const bf8*)((const char*)lds + r * 128 + ((c ^ (r & 7)) << 4));
}

// ---------------- fused f32 -> bf16 converter (all 4 weight tensors, 1 launch) -------
__global__ __launch_bounds__(256) void conv4_k(
    const float* __restrict__ s0, u16* __restrict__ d0, int n0,
    const float* __restrict__ s1, u16* __restrict__ d1, int n1,
    const float* __restrict__ s2, u16* __restrict__ d2, int n2,
    const float* __restrict__ s3, u16* __restrict__ d3, int n3) {
  int i = blockIdx.x * 256 + threadIdx.x;
  const float* s; u16* d;
  if (i < n0) { s = s0; d = d0; }
  else if (i < n0 + n1) { i -= n0; s = s1; d = d1; }
  else if (i < n0 + n1 + n2) { i -= n0 + n1; s = s2; d = d2; }
  else if (i < n0 + n1 + n2 + n3) { i -= n0 + n1 + n2; s = s3; d = d3; }
  else return;
  float4 v = ((const float4*)s)[i];
  union { u16 sh[4]; uint2 u; } o;
  o.sh[0] = f2b(v.x); o.sh[1] = f2b(v.y); o.sh[2] = f2b(v.z); o.sh[3] = f2b(v.w);
  ((uint2*)d)[i] = o.u;
}

// ---------------- LayerNorm (f32 or bf16 in) -> bf16 out ----------------
template <int INF32>
__global__ __launch_bounds__(256) void ln_bf16_k(const void* __restrict__ in,
                                                 const float* __restrict__ w,
                                                 const float* __restrict__ b,
                                                 u16* __restrict__ out) {
  const long row = blockIdx.x;
  const int t = threadIdx.x;
  float v[3];
  float s = 0.f, q = 0.f;
#pragma unroll
  for (int i = 0; i < 3; ++i) {
    if (INF32) v[i] = ((const float*)in)[row * 768 + t + 256 * i];
    else       v[i] = b2f(((const u16*)in)[row * 768 + t + 256 * i]);
    s += v[i]; q += v[i] * v[i];
  }
#pragma unroll
  for (int off = 1; off < 64; off <<= 1) { s += __shfl_xor(s, off); q += __shfl_xor(q, off); }
  __shared__ float rs[4], rq[4];
  const int wave = t >> 6, lane = t & 63;
  if (lane == 0) { rs[wave] = s; rq[wave] = q; }
  __syncthreads();
  s = rs[0] + rs[1] + rs[2] + rs[3];
  q = rq[0] + rq[1] + rq[2] + rq[3];
  const float mean = s * (1.0f / 768.0f);
  const float var = q * (1.0f / 768.0f) - mean * mean;
  const float rstd = rsqrtf(var + 1e-5f);
  u16* orow = out + row * 768;
#pragma unroll
  for (int i = 0; i < 3; ++i) {
    const int c = t + 256 * i;
    orow[c] = f2b((v[i] - mean) * rstd * w[c] + b[c]);
  }
}

// ---------------- bf16 transpose [4096][768] -> [768][4096]; also zeros rsum ---------
__global__ __launch_bounds__(256) void transp_k(const u16* __restrict__ in,
                                                u16* __restrict__ out,
                                                float* __restrict__ rsum) {
  const int d0 = blockIdx.x * 64, s0 = blockIdx.y * 64;
  const int t = threadIdx.x;
  {
    const int bid = blockIdx.x + 12 * blockIdx.y;
    if (bid < 16) rsum[bid * 256 + t] = 0.f;
  }
  __shared__ u16 T[64][72];
  {
    const int r = t >> 3, c8 = (t & 7) * 8;
#pragma unroll
    for (int p = 0; p < 2; ++p) {
      const int rr = r + 32 * p;
      *(uint4*)&T[rr][c8] = *(const uint4*)&in[(long)(s0 + rr) * 768 + d0 + c8];
    }
  }
  __syncthreads();
  {
    const int d = t >> 3, s8 = (t & 7) * 8;
#pragma unroll
    for (int p = 0; p < 2; ++p) {
      const int dd = d + 32 * p;
      u16 tmp[8];
#pragma unroll
      for (int e = 0; e < 8; ++e) tmp[e] = T[s8 + e][dd];
      *(uint4*)&out[(long)(d0 + dd) * 4096 + s0 + s8] = *(uint4*)tmp;
    }
  }
}

// ---------------- MFMA GEMM (dbuf counted-vmcnt, proven; BK templated) ---------------
// C = A[M,K] @ Bt[N,K]^T. TM x 128 tile, dbuf XOR-swizzled LDS, counted vmcnt,
// pointer-increment staging, hoisted frag offsets, XCD-chunk + group-N decode (G=8).
// BK=64: 128B LDS rows (8 chunks, swz cs^(r&7)), 32 MFMA/step.
// BK=32: 64B LDS rows (4 chunks, swz cs^((r>>1)&3), 2-way = free), 16 MFMA/step,
//        half the LDS -> 4 blocks/CU (for the capacity-capped FF1).
// EPI: 0 = merged proj: col<768 -> q*(0.125*log2e); <1536 -> k; <1600 -> tanh -> phase
//      3 = bias + gelu -> O0 bf16
//      5 = rowscale by rcp(rsum) + f32 res -> O0 bf16 (PV; bias arg = rsum[bz*M+row])
//      6 = bias + bf16 res -> O0 f32 (FF2; res points to bf16)
template <int EPI, int TM, int BK>
__global__ __launch_bounds__(256) void mgemm5_k(
    const u16* __restrict__ A, int lda, long sA,
    const u16* __restrict__ B, int ldb, long sB,
    const float* __restrict__ bias,
    const float* __restrict__ res, long sR,
    void* __restrict__ O0, long sO, void* __restrict__ O1, void* __restrict__ O2,
    const int M, const int N, const int K) {
  constexpr int WR = (TM == 128) ? 2 : 1;
  constexpr int WC = 4 / WR;
  constexpr int MR = TM / (WR * 16);      // 4
  constexpr int NR = 128 / (WC * 16);     // 4 (TM=128) or 2 (TM=64)
  constexpr int CPR = BK / 8;             // 16B chunks per LDS row (8 or 4)
  constexpr int AISS = TM * BK / 2048;    // staging issues per wave for A
  constexpr int BISS = 128 * BK / 2048;
  constexpr int NS = AISS + BISS;         // loads in flight for one tile
  constexpr int AW = TM * BK;             // elements per A buffer
  constexpr int BW = 128 * BK;
  constexpr int SH = BK / 32;             // MFMA K-halves per step (2 or 1)
  __shared__ u16 As[2 * AW];
  __shared__ u16 Bs[2 * BW];
  const int t = threadIdx.x;
  const int wv = t >> 6, lane = t & 63;
  const int lr = lane & 15, lg = lane >> 4;
  const int wr = wv / WC, wc = wv % WC;
  const int wrow0 = wr * (MR * 16), wcol0 = wc * (NR * 16);

  // XCD chunking (nwg%8==0) + triton-style group along N inside the chunk.
  const int gx = gridDim.x, gy = gridDim.y;
  const int nwg = gx * gy;
  const int cpx = nwg >> 3;
  const int flat = blockIdx.x + gx * blockIdx.y;
  const int nf = (flat & 7) * cpx + (flat >> 3);
  constexpr int G = 8;
  const int npg = G * gy;
  const int grp = nf / npg;
  const int firstn = grp * G;
  const int gsz = (gx - firstn < G) ? (gx - firstn) : G;
  const int rem = nf - grp * npg;
  const int m0 = (rem / gsz) * TM;
  const int n0 = (firstn + rem % gsz) * 128;

  const int bz = blockIdx.z;
  const u16* Ab = A + (long)bz * sA + (long)m0 * lda;
  const u16* Bb = B + (long)bz * sB + (long)n0 * ldb;
  const long zR = (long)bz * sR, zO = (long)bz * sO;

  // staging pointers: computed once, advanced by BK elements per K-step
  const u16* ga[AISS];
  const u16* gb[BISS];
#pragma unroll
  for (int is = 0; is < AISS; ++is) {
    const int idx = is * 256 + wv * 64 + lane;
    const int r = idx / CPR, cs = idx % CPR;
    const int swz = (CPR == 8) ? (cs ^ (r & 7)) : (cs ^ ((r >> 1) & 3));
    ga[is] = Ab + (long)r * lda + (swz << 3);
  }
#pragma unroll
  for (int is = 0; is < BISS; ++is) {
    const int idx = is * 256 + wv * 64 + lane;
    const int r = idx / CPR, cs = idx % CPR;
    const int swz = (CPR == 8) ? (cs ^ (r & 7)) : (cs ^ ((r >> 1) & 3));
    gb[is] = Bb + (long)r * ldb + (swz << 3);
  }

  // hoisted frag byte offsets (within one buffer), s = K-half
  int offA[SH][MR], offB[SH][NR];
#pragma unroll
  for (int i = 0; i < MR; ++i) {
    const int r = wrow0 + i * 16 + lr;
#pragma unroll
    for (int s = 0; s < SH; ++s) {
      const int chunk = (CPR == 8) ? ((s * 4 + lg) ^ (r & 7)) : (lg ^ ((r >> 1) & 3));
      offA[s][i] = r * (BK * 2) + (chunk << 4);
    }
  }
#pragma unroll
  for (int j = 0; j < NR; ++j) {
    const int r = wcol0 + j * 16 + lr;
#pragma unroll
    for (int s = 0; s < SH; ++s) {
      const int chunk = (CPR == 8) ? ((s * 4 + lg) ^ (r & 7)) : (lg ^ ((r >> 1) & 3));
      offB[s][j] = r * (BK * 2) + (chunk << 4);
    }
  }

  f4 acc[MR][NR];
  const f4 fz = {0.f, 0.f, 0.f, 0.f};
#pragma unroll
  for (int i = 0; i < MR; ++i)
#pragma unroll
    for (int j = 0; j < NR; ++j) acc[i][j] = fz;

  // prologue: stage tile 0 into buf 0
#pragma unroll
  for (int is = 0; is < AISS; ++is) {
    GLOAD_LDS16(ga[is], (char*)As + is * 4096 + wv * 1024);
    ga[is] += BK;
  }
#pragma unroll
  for (int is = 0; is < BISS; ++is) {
    GLOAD_LDS16(gb[is], (char*)Bs + is * 4096 + wv * 1024);
    gb[is] += BK;
  }

  const int NT = K / BK;
  int cur = 0;
  for (int kt = 0; kt < NT; ++kt) {
    if (kt + 1 < NT) {
      char* bufA = (char*)(As + (cur ^ 1) * AW);
      char* bufB = (char*)(Bs + (cur ^ 1) * BW);
#pragma unroll
      for (int is = 0; is < AISS; ++is) {
        GLOAD_LDS16(ga[is], bufA + is * 4096 + wv * 1024);
        ga[is] += BK;
      }
#pragma unroll
      for (int is = 0; is < BISS; ++is) {
        GLOAD_LDS16(gb[is], bufB + is * 4096 + wv * 1024);
        gb[is] += BK;
      }
      waitvm<NS>();   // tile kt landed; tile kt+1 stays in flight
    } else {
      waitvm<0>();
    }
    __builtin_amdgcn_s_barrier();
    const char* a = (const char*)(As + cur * AW);
    const char* b = (const char*)(Bs + cur * BW);
    bf8 af[SH][MR], bf[SH][NR];
#pragma unroll
    for (int s = 0; s < SH; ++s) {
#pragma unroll
      for (int i = 0; i < MR; ++i) af[s][i] = *(const bf8*)(a + offA[s][i]);
#pragma unroll
      for (int j = 0; j < NR; ++j) bf[s][j] = *(const bf8*)(b + offB[s][j]);
    }
#pragma unroll
    for (int s = 0; s < SH; ++s)
#pragma unroll
      for (int i = 0; i < MR; ++i)
#pragma unroll
        for (int j = 0; j < NR; ++j)
          acc[i][j] = __builtin_amdgcn_mfma_f32_16x16x32_bf16(af[s][i], bf[s][j], acc[i][j], 0, 0, 0);
    __builtin_amdgcn_s_barrier();   // WAR: all waves done reading buf[cur]
    cur ^= 1;
  }

#pragma unroll
  for (int i = 0; i < MR; ++i) {
    const int gr0 = m0 + wrow0 + i * 16 + lg * 4;
#pragma unroll
    for (int j = 0; j < NR; ++j) {
      const int gc = n0 + wcol0 + j * 16 + lr;
#pragma unroll
      for (int r = 0; r < 4; ++r) {
        const long row = gr0 + r;
        float v = acc[i][j][r];
        if (EPI == 0) {
          if (gc < 1536) {
            v += bias[gc];
            if (gc < 768) ((u16*)O0)[row * 768 + gc] = f2b(v * (0.125f * LOG2E));
            else          ((u16*)O1)[row * 768 + gc - 768] = f2b(v);
          } else if (gc < 1600) {
            ((u16*)O2)[row * 64 + gc - 1536] = f2b(fast_tanh(v));
          }
        } else if (EPI == 3) {
          ((u16*)O0)[row * N + gc] = f2b(fast_gelu(v + bias[gc]));
        } else if (EPI == 5) {  // PV: rowscale + f32 residual -> bf16 out
          const float sc = rcp_f(bias[(long)bz * M + row]);
          ((u16*)O0)[zO + row * N + gc] = f2b(v * sc + res[zR + row * N + gc]);
        } else {  // 6: FF2: bias + bf16 residual -> f32 out
          ((float*)O0)[row * N + gc] = v + bias[gc] + b2f(((const u16*)res)[row * N + gc]);
        }
      }
    }
  }
}

// ---------------- attention stats v4: XCD-grouped 1D grid ---------------------------
__global__ __launch_bounds__(256) void attn_stats4(const u16* __restrict__ qb,
                                                   const u16* __restrict__ kb,
                                                   float* __restrict__ Ms_g) {
  const int bid = blockIdx.x;
  const int s8 = bid & 7, idx = bid >> 3;        // idx in [0,96)
  const int qt = idx & 31;
  const int combo = s8 * 3 + (idx >> 5);         // [0,24)
  const int h = combo % 12, b = combo / 12;
  const int t = threadIdx.x, wv = t >> 6, lane = t & 63;
  const int lr = lane & 15, lg = lane >> 4;
  __shared__ u16 Qs[64 * 64];
  __shared__ u16 Ks[2][128 * 64];
  __shared__ float zbuf[4][64];
  const long q0 = (long)b * 2048 + qt * 64;
  const long kbase = ((long)b * 2048) * 768 + h * 64;
  stage_sw<2>(qb + q0 * 768 + h * 64, 768, Qs, wv, lane);
  stage_sw<4>(kb + kbase, 768, Ks[0], wv, lane);
  waitvm<4>();  // Q's 2 loads retired (FIFO); K0's 4 may stay in flight
  __builtin_amdgcn_s_barrier();

  bf8 aq[4][2];
#pragma unroll
  for (int i = 0; i < 4; ++i)
#pragma unroll
    for (int kk = 0; kk < 2; ++kk)
      aq[i][kk] = frag_sw(Qs, i * 16 + lr, kk * 4 + lg);

  float zp[4][4];
#pragma unroll
  for (int i = 0; i < 4; ++i)
#pragma unroll
    for (int r = 0; r < 4; ++r) zp[i][r] = 0.f;

  const f4 fz = {0.f, 0.f, 0.f, 0.f};
  int cur = 0;
  for (int kt = 0; kt < 16; ++kt) {
    if (kt < 15) {
      stage_sw<4>(kb + kbase + (long)(kt + 1) * 128 * 768, 768, Ks[cur ^ 1], wv, lane);
      waitvm<4>();
    } else {
      waitvm<0>();
    }
    __builtin_amdgcn_s_barrier();
#pragma unroll
    for (int j = 0; j < 2; ++j) {
      const int krow = wv * 32 + j * 16 + lr;
      const bf8 b0 = frag_sw(Ks[cur], krow, lg);
      const bf8 b1 = frag_sw(Ks[cur], krow, 4 + lg);
#pragma unroll
      for (int i = 0; i < 4; ++i) {
        f4 s = fz;
        s = __builtin_amdgcn_mfma_f32_16x16x32_bf16(aq[i][0], b0, s, 0, 0, 0);
        s = __builtin_amdgcn_mfma_f32_16x16x32_bf16(aq[i][1], b1, s, 0, 0, 0);
#pragma unroll
        for (int r = 0; r < 4; ++r) zp[i][r] += ex2(s[r]);
      }
    }
    __builtin_amdgcn_s_barrier();
    cur ^= 1;
  }
#pragma unroll
  for (int i = 0; i < 4; ++i)
#pragma unroll
    for (int r = 0; r < 4; ++r) {
      float z = zp[i][r];
      z += __shfl_xor(z, 1); z += __shfl_xor(z, 2);
      z += __shfl_xor(z, 4); z += __shfl_xor(z, 8);
      zp[i][r] = z;
    }
  if (lr == 0) {
#pragma unroll
    for (int i = 0; i < 4; ++i)
#pragma unroll
      for (int r = 0; r < 4; ++r)
        zbuf[wv][i * 16 + lg * 4 + r] = zp[i][r];
  }
  __syncthreads();
  if (t < 64) {
    const float Z = zbuf[0][t] + zbuf[1][t] + zbuf[2][t] + zbuf[3][t];
    Ms_g[((long)(b * 12 + h)) * 2048 + qt * 64 + t] = log2f(12.0f * Z);
  }
}

// ---------------- blend-pre v10: XCD-grouped 1D grid, dbuf counted-vmcnt --------------
__global__ __launch_bounds__(256) void blendpre10(const u16* __restrict__ qb,
                                                  const u16* __restrict__ kb,
                                                  const u16* __restrict__ ph,
                                                  const float* __restrict__ Ms_g,
                                                  const float* __restrict__ alpha_p,
                                                  u16* __restrict__ eb,
                                                  float* __restrict__ rsum) {
  const int bid = blockIdx.x;
  const int s8 = bid & 7, idx = bid >> 3;        // idx in [0,64)
  const int kt = ((s8 & 1) << 3) | (idx & 7);
  const int qt = (((s8 >> 1) & 1) << 3) | (idx >> 3);
  const int b = s8 >> 2;
  const int t = threadIdx.x, wv = t >> 6, lane = t & 63;
  const int lr = lane & 15, lg = lane >> 4;
  const int wr = wv >> 1, wc = wv & 1;
  const int q0 = qt * 128, k0 = kt * 128;
  __shared__ u16 Qs[2][128 * 64];
  __shared__ u16 Ks[2][128 * 64];
  __shared__ float Ms[12][128];
  for (int i2 = t; i2 < 1536; i2 += 256)
    Ms[i2 >> 7][i2 & 127] = Ms_g[((long)(b * 12 + (i2 >> 7))) * 2048 + q0 + (i2 & 127)];
  asm volatile("s_waitcnt vmcnt(0) lgkmcnt(0)" ::: "memory");
  __builtin_amdgcn_s_barrier();   // Ms visible to all waves
  const float a2 = alpha_p[0] * 0.5f * LOG2E;

  f4 acc[4][4];
  const f4 fz = {0.f, 0.f, 0.f, 0.f};
#pragma unroll
  for (int i = 0; i < 4; ++i)
#pragma unroll
    for (int j = 0; j < 4; ++j) acc[i][j] = fz;

  const long qrow0 = (long)b * 2048 + q0;
  const long krow0 = (long)b * 2048 + k0;

  stage_sw<4>(qb + qrow0 * 768, 768, Qs[0], wv, lane);
  stage_sw<4>(kb + krow0 * 768, 768, Ks[0], wv, lane);

  int cur = 0;
  for (int h = 0; h < 12; ++h) {
    if (h < 11) {
      stage_sw<4>(qb + qrow0 * 768 + (h + 1) * 64, 768, Qs[cur ^ 1], wv, lane);
      stage_sw<4>(kb + krow0 * 768 + (h + 1) * 64, 768, Ks[cur ^ 1], wv, lane);
      waitvm<8>();
    } else {
      waitvm<0>();
    }
    __builtin_amdgcn_s_barrier();
    bf8 aq0[4], aq1[4], bk0[4], bk1[4];
#pragma unroll
    for (int i = 0; i < 4; ++i) {
      aq0[i] = frag_sw(Qs[cur], wr * 64 + i * 16 + lr, lg);
      aq1[i] = frag_sw(Qs[cur], wr * 64 + i * 16 + lr, 4 + lg);
    }
#pragma unroll
    for (int j = 0; j < 4; ++j) {
      bk0[j] = frag_sw(Ks[cur], wc * 64 + j * 16 + lr, lg);
      bk1[j] = frag_sw(Ks[cur], wc * 64 + j * 16 + lr, 4 + lg);
    }
#pragma unroll
    for (int i = 0; i < 4; ++i) {
      const f4 mv = *(const f4*)&Ms[h][wr * 64 + i * 16 + lg * 4];
      const f4 cin = fz - mv;  // fold -M into the accumulator init
#pragma unroll
      for (int j = 0; j < 4; ++j) {
        f4 s = __builtin_amdgcn_mfma_f32_16x16x32_bf16(aq0[i], bk0[j], cin, 0, 0, 0);
        s = __builtin_amdgcn_mfma_f32_16x16x32_bf16(aq1[i], bk1[j], s, 0, 0, 0);
#pragma unroll
        for (int r = 0; r < 4; ++r) acc[i][j][r] += ex2(s[r]);
      }
    }
    __builtin_amdgcn_s_barrier();
    cur ^= 1;
  }

  float rs[4][4];
#pragma unroll
  for (int i = 0; i < 4; ++i)
#pragma unroll
    for (int r = 0; r < 4; ++r) rs[i][r] = 0.f;

#pragma unroll
  for (int i = 0; i < 4; ++i) {
    const u16* pa = ph + (qrow0 + wr * 64 + i * 16 + lr) * 64;
    const bf8 pa0 = *(const bf8*)(pa + lg * 8);
    const bf8 pa1 = *(const bf8*)(pa + 32 + lg * 8);
#pragma unroll
    for (int j = 0; j < 4; ++j) {
      const u16* pb = ph + (krow0 + wc * 64 + j * 16 + lr) * 64;
      const bf8 pb0 = *(const bf8*)(pb + lg * 8);
      const bf8 pb1 = *(const bf8*)(pb + 32 + lg * 8);
      f4 coh = fz;
      coh = __builtin_amdgcn_mfma_f32_16x16x32_bf16(pa0, pb0, coh, 0, 0, 0);
      coh = __builtin_amdgcn_mfma_f32_16x16x32_bf16(pa1, pb1, coh, 0, 0, 0);
#pragma unroll
      for (int r = 0; r < 4; ++r) {
        const long row = qrow0 + wr * 64 + i * 16 + lg * 4 + r;
        const int col = k0 + wc * 64 + j * 16 + lr;
        const float e = (acc[i][j][r] + 1e-6f) * ex2(a2 * (coh[r] + 1.0f));
        eb[row * 2048 + col] = f2b(e);
        rs[i][r] += e;
      }
    }
  }
  // per-row partial sums: reduce over the 16 lanes sharing (lg, row), one atomic each
#pragma unroll
  for (int i = 0; i < 4; ++i)
#pragma unroll
    for (int r = 0; r < 4; ++r) {
      float v = rs[i][r];
      v += __shfl_xor(v, 1); v += __shfl_xor(v, 2);
      v += __shfl_xor(v, 4); v += __shfl_xor(v, 8);
      if (lr == 0)
        atomicAdd(&rsum[qrow0 + wr * 64 + i * 16 + lg * 4 + r], v);
    }
}

// ---------------- launch ----------------
extern "C" void kernel_launch(void* const* d_in, const int* in_sizes, int n_in,
                              void* d_out, int out_size, void* d_ws, size_t ws_size,
                              hipStream_t stream) {
  (void)in_sizes; (void)n_in; (void)out_size; (void)ws_size;
  const float* x         = (const float*)d_in[0];
  const float* ln1_w     = (const float*)d_in[1];
  const float* ln1_b     = (const float*)d_in[2];
  const float* in_proj_w = (const float*)d_in[3];
  const float* in_proj_b = (const float*)d_in[4];
  const float* phase_w   = (const float*)d_in[5];
  const float* alpha_p   = (const float*)d_in[6];
  const float* ff_w1     = (const float*)d_in[7];
  const float* ff_b1     = (const float*)d_in[8];
  const float* ff_w2     = (const float*)d_in[9];
  const float* ff_b2     = (const float*)d_in[10];
  const float* ln2_w     = (const float*)d_in[11];
  const float* ln2_b     = (const float*)d_in[12];
  float* out = (float*)d_out;

  char* w = (char*)d_ws;
  u16*   xn_b  = (u16*)w;            w += 6291456;   // [4096][768] bf16
  u16*   xnT_b = (u16*)w;            w += 6291456;   // [768][4096] bf16
  u16*   ph_b  = (u16*)w;            w += 524288;    // [4096][64] bf16
  float* Ms_g  = (float*)w;          w += 196608;    // [2,12,2048] f32
  u16*   xmid_b = (u16*)w;           w += 12582912;  // [4096][768] bf16 (region kept at old size)
  char* big = w;
  u16* q_b  = (u16*)big;                              // [4096][768] bf16
  u16* k_b  = (u16*)(big + 6291456);                  // [4096][768] bf16
  u16* eb_b = (u16*)(big + 12582912);                 // [2,2048,2048] bf16 (unnormalized e)
  char* tail = big + 12582912 + 16777216;
  u16* wcat_b = (u16*)tail;                           // [1664][768] bf16 (dead after proj)
  float* rsum = (float*)(tail + 2555904);             // [4096] f32 (row sums)
  u16* h_b  = (u16*)big;                              // [4096][3072] bf16 (overlays q,k,eb)
  char* wtail = tail + 16777216;
  u16* wff1_b = (u16*)wtail;                          // [3072][768] bf16
  u16* wff2_b = (u16*)(wtail + 4718592);              // [768][3072] bf16
  u16* x2n_b = xn_b;

  // one fused conversion launch: in_proj(+phase appended) | ff_w1 | ff_w2
  conv4_k<<<(1486848 + 255) / 256, 256, 0, stream>>>(
      in_proj_w, wcat_b, 1536 * 768 / 4,
      phase_w, wcat_b + 1536 * 768, 64 * 768 / 4,
      ff_w1, wff1_b, 3072 * 768 / 4,
      ff_w2, wff2_b, 768 * 3072 / 4);

  ln_bf16_k<1><<<4096, 256, 0, stream>>>(x, ln1_w, ln1_b, xn_b);

  // merged QK + phase projection: N = 1536 (q,k) + 64 (phase) padded to 1664
  mgemm5_k<0, 128, 64><<<dim3(13, 32, 1), 256, 0, stream>>>(
      xn_b, 768, 0, wcat_b, 768, 0, in_proj_b, nullptr, 0,
      q_b, 0, k_b, ph_b, 4096, 1664, 768);

  transp_k<<<dim3(12, 64), 256, 0, stream>>>(xn_b, xnT_b, rsum);

  attn_stats4<<<768, 256, 0, stream>>>(q_b, k_b, Ms_g);

  blendpre10<<<512, 256, 0, stream>>>(q_b, k_b, ph_b, Ms_g, alpha_p, eb_b, rsum);

  // PV: out bf16 (xmid_b), residual x (f32)
  mgemm5_k<5, 64, 64><<<dim3(6, 32, 2), 256, 0, stream>>>(
      eb_b, 2048, 2048L * 2048, xnT_b, 4096, 2048, rsum, x, 2048L * 768,
      xmid_b, 2048L * 768, nullptr, nullptr, 2048, 768, 2048);

  ln_bf16_k<0><<<4096, 256, 0, stream>>>(xmid_b, ln2_w, ln2_b, x2n_b);

  // FF1: BK=32 (half LDS -> 4 blocks/CU; this GEMM is capacity-capped at 768 blocks)
  mgemm5_k<3, 128, 32><<<dim3(24, 32, 1), 256, 0, stream>>>(
      x2n_b, 768, 0, wff1_b, 768, 0, ff_b1, nullptr, 0,
      h_b, 0, nullptr, nullptr, 4096, 3072, 768);

  // FF2: bias + bf16 residual (xmid_b) -> f32 out
  mgemm5_k<6, 64, 64><<<dim3(6, 64, 1), 256, 0, stream>>>(
      h_b, 3072, 0, wff2_b, 3072, 0, ff_b2, (const float*)xmid_b, 0,
      out, 0, nullptr, nullptr, 4096, 768, 3072);
}